// Round 12
// baseline (144.376 us; speedup 1.0000x reference)
//
#include <hip/hip_runtime.h>

#define BB 4
#define NN 256
#define DMM 128
#define DEE 8
#define HH 8
#define DD 16
#define LAYERS 2
#define SCALE 0.25f
#define PS 260               // padded LDS stride (floats); 260%4==0 so float4-aligned rows
#define SS (BB*NN*DMM)       // 131072 floats per per-layer buffer

// K stored TRANSPOSED: kT[b][d][j] at ((b*DMM + d)*NN + j)  (R7 win: lines/instr).
// V12 = V11 (XCD swizzle + es hoist + paired K^T stores) with k_mid restructured
// to 1 ROW PER BLOCK (1024 x 256t): the measured-fastest per-row attn structure
// (k_attn form, ~8 blocks/CU via 19KB LDS) + 4-wave proj(l1) tail per row.

struct Params {
  const float *nodes, *edges, *adjacency;
  const float *Wq, *bq, *Wk, *bk, *Wv, *bv, *We, *be, *Wres, *bres, *Wgate, *lng, *lnb;
  const float *src;
  float *q, *k, *v, *res;
  float *out;
  int layer;
};

// ---------------- D1: q,k,v,res = src @ W + b (layer 0); 512 blocks x 2 rows ----------------
__global__ __launch_bounds__(256) void k_proj(Params P){
  const int t = threadIdx.x;
  const int m = t >> 6;
  const int cp = t & 63;
  const int bid = blockIdx.x;
  const int obid = (bid & 7)*64 + (bid >> 3);    // XCD swizzle
  const int row0 = obid * 2;
  const int l = P.layer;
  const float *W, *bia; float* dst;
  if (m==0){ W = P.Wq + l*DMM*DMM; bia = P.bq + l*DMM; dst = P.q; }
  else if (m==1){ W = P.Wk + l*DMM*DMM; bia = P.bk + l*DMM; dst = P.k; }
  else if (m==2){ W = P.Wv + l*DMM*DMM; bia = P.bv + l*DMM; dst = P.v; }
  else { W = P.Wres + l*DMM*DMM; bia = P.bres + l*DMM; dst = P.res; }
  const float2 bv2 = *(const float2*)(bia + 2*cp);
  float a00=bv2.x, a01=bv2.y, a10=bv2.x, a11=bv2.y;
  const float2* W2 = (const float2*)W;
  const float* xr = P.src + (size_t)row0*DMM;
  #pragma unroll 8
  for (int kk=0; kk<DMM; kk++){
    float2 w = W2[kk*64+cp];
    float x0 = xr[kk], x1 = xr[DMM+kk];
    a00 += x0*w.x; a01 += x0*w.y;
    a10 += x1*w.x; a11 += x1*w.y;
  }
  if (m==1){
    const int b = row0 >> 8, i0 = row0 & 255;   // i0 even -> float2-aligned
    float* kT = dst + ((size_t)b*DMM + 2*cp)*NN;
    *(float2*)(kT + i0)      = make_float2(a00, a10);
    *(float2*)(kT + NN + i0) = make_float2(a01, a11);
  } else {
    *(float2*)(dst + (size_t)row0*DMM     + 2*cp) = make_float2(a00,a01);
    *(float2*)(dst + (size_t)(row0+1)*DMM + 2*cp) = make_float2(a10,a11);
  }
}

// ---------------- D2: attn(l=0) 1 row/block + proj(l=1) for that row ----------------
// 1024 blocks x 256 threads. NOTE: reference's mean-shift cancels exactly in
// _adj_softmax - no shift applied.
__global__ __launch_bounds__(256) void k_mid(Params P){
  const int t = threadIdx.x;
  const int bid = blockIdx.x;
  const int obid = (bid & 7)*128 + (bid >> 3);   // XCD swizzle: XCD x owns rows [128x,128x+128)
  const int row = obid;
  const int b = row >> 8;
  const int i = row & 255;

  __shared__ float xloc[128];      // x1 row (attn0 output)
  __shared__ float qs[128];
  __shared__ float qwe_s[64];
  __shared__ float qbe_s[8];
  __shared__ float es[8*PS];
  __shared__ float ps[8*PS];
  __shared__ float ssum_s[8];
  __shared__ float g_s[64];
  __shared__ float res_s[128];
  __shared__ float red_a[2], red_b[2], red_c[2];

  if (t < 128) qs[t]        = P.q  [(size_t)row*DMM + t];
  else         res_s[t-128] = P.res[(size_t)row*DMM + (t-128)];
  {
    const int j = t;
    const float4* er4 = (const float4*)(P.edges + ((size_t)row*NN + j)*DEE);
    float4 e0 = er4[0], e1 = er4[1];
    es[0*PS+j]=e0.x; es[1*PS+j]=e0.y; es[2*PS+j]=e0.z; es[3*PS+j]=e0.w;
    es[4*PS+j]=e1.x; es[5*PS+j]=e1.y; es[6*PS+j]=e1.z; es[7*PS+j]=e1.w;
  }
  __syncthreads();
  if (t < 64){
    const int h = t>>3, c = t&7;
    const float* Wer = P.We + c*DMM + h*DD;
    float a = 0.f;
    #pragma unroll
    for (int d=0; d<DD; d++) a += qs[h*DD+d]*Wer[d];
    qwe_s[t] = a;
    if (c==0){
      const float* ber = P.be + h*DD;
      float a2 = 0.f;
      #pragma unroll
      for (int d=0; d<DD; d++) a2 += qs[h*DD+d]*ber[d];
      qbe_s[h] = a2;
    }
  }
  __syncthreads();

  // ---- phase 1: wave dp -> heads {2dp,2dp+1}; lane jg -> cols 4jg..4jg+3 ----
  {
    const int dp = t>>6, jg = t&63;
    const int J = 4*jg;
    const float4 av = *(const float4*)(P.adjacency + (size_t)row*NN + J);
    float4 ec4[8];                       // es hoist
    #pragma unroll
    for (int c=0; c<8; c++) ec4[c] = *(const float4*)(&es[c*PS + J]);
    float hsum[2];
    #pragma unroll
    for (int hh=0; hh<2; hh++){
      const int h = 2*dp+hh;
      float qh[16];
      #pragma unroll
      for (int d=0; d<16; d++) qh[d] = qs[h*DD+d];
      float s0=qbe_s[h]; float s1=s0, s2=s0, s3=s0;
      const float* kbase = P.k + ((size_t)b*DMM + h*DD)*NN + J;
      #pragma unroll
      for (int db=0; db<2; db++){
        float4 krg[8];
        #pragma unroll
        for (int d=0; d<8; d++) krg[d] = *(const float4*)(kbase + (size_t)(db*8+d)*NN);
        #pragma unroll
        for (int d=0; d<8; d++){
          float qv = qh[db*8+d];
          s0 += qv*krg[d].x; s1 += qv*krg[d].y; s2 += qv*krg[d].z; s3 += qv*krg[d].w;
        }
      }
      #pragma unroll
      for (int c=0; c<8; c++){
        float wv = qwe_s[h*8+c];
        s0 += wv*ec4[c].x; s1 += wv*ec4[c].y; s2 += wv*ec4[c].z; s3 += wv*ec4[c].w;
      }
      float4 p;
      p.x = __expf(s0*SCALE)*av.x;
      p.y = __expf(s1*SCALE)*av.y;
      p.z = __expf(s2*SCALE)*av.z;
      p.w = __expf(s3*SCALE)*av.w;
      *(float4*)(&ps[h*PS + J]) = p;
      hsum[hh] = (p.x+p.y)+(p.z+p.w);
    }
    float v0 = hsum[0], v1 = hsum[1];
    #pragma unroll
    for (int off=32; off; off>>=1){ v0 += __shfl_xor(v0,off,64); v1 += __shfl_xor(v1,off,64); }
    if (jg==0){ ssum_s[2*dp] = v0; ssum_s[2*dp+1] = v1; }
  }
  __syncthreads();

  // ---- phase 2: pv (t<128), g (128<=t<192) ----
  float pv = 0.f;
  if (t < 128){
    const int h = t>>4;
    const float* vcol = P.v + (size_t)b*NN*DMM + t;     // h*DD+d == t
    const float4* pr = (const float4*)(ps + h*PS);
    #pragma unroll 4
    for (int jq=0; jq<64; jq++){
      float4 pp = pr[jq];
      const float* vv = vcol + jq*4*DMM;
      pv += pp.x*vv[0] + pp.y*vv[DMM] + pp.z*vv[2*DMM] + pp.w*vv[3*DMM];
    }
  } else if (t < 192){
    const int h=(t-128)>>3, c=(t-128)&7;
    const float4* pr = (const float4*)(ps + h*PS);
    const float4* er = (const float4*)(es + c*PS);
    float g=0.f;
    #pragma unroll 4
    for (int jq=0; jq<64; jq++){
      float4 pp=pr[jq], ee=er[jq];
      g += pp.x*ee.x + pp.y*ee.y + pp.z*ee.z + pp.w*ee.w;
    }
    g_s[h*8+c]=g;
  }
  __syncthreads();

  // ---- phase 3: assemble out, gate reduction (layer 0 weights) ----
  float o=0.f, rr=0.f;
  if (t<128){
    const int h = t>>4;
    const float* Wec = P.We + t;
    float eacc=0.f;
    #pragma unroll
    for (int c=0;c<8;c++) eacc += Wec[c*DMM]*g_s[h*8+c];
    const float ssum = ssum_s[h];
    const float denom = (ssum==0.f)?1.f:ssum;
    const float bev = P.be[t];
    o = (pv + eacc + ssum*bev)/denom;
    rr = res_s[t];
    const float* Wg = P.Wgate;
    float contrib = o*Wg[t] + rr*Wg[DMM+t] + (o-rr)*Wg[2*DMM+t];
    #pragma unroll
    for (int off=32; off; off>>=1) contrib += __shfl_xor(contrib, off, 64);
    if ((t&63)==0) red_a[t>>6]=contrib;
  }
  __syncthreads();

  float y=0.f;
  if (t<128){
    const float gs = red_a[0]+red_a[1];
    const float gate = 1.f/(1.f+__expf(-gs));
    y = o*gate + rr*(1.f-gate);
    float s1=y, s2=y*y;
    #pragma unroll
    for (int off=32; off; off>>=1){ s1+=__shfl_xor(s1,off,64); s2+=__shfl_xor(s2,off,64); }
    if ((t&63)==0){ red_b[t>>6]=s1; red_c[t>>6]=s2; }
  }
  __syncthreads();

  if (t<128){
    const float mu  = (red_b[0]+red_b[1])*(1.f/128.f);
    const float var = (red_c[0]+red_c[1])*(1.f/128.f) - mu*mu;
    const float inv = rsqrtf(var+1e-5f);
    float yn = (y-mu)*inv*P.lng[t] + P.lnb[t];
    xloc[t] = fmaxf(yn, 0.f);
  }
  __syncthreads();

  // ---- proj(l=1) for this row: wave m -> matrix m; lane cp -> cols 2cp,2cp+1 ----
  {
    const int m = t>>6, cp = t&63;
    const float *W, *bia; float* dst;
    if (m==0){ W=P.Wq+DMM*DMM;   bia=P.bq+DMM;   dst=P.q;   }
    else if (m==1){ W=P.Wk+DMM*DMM;   bia=P.bk+DMM;   dst=P.k;   }
    else if (m==2){ W=P.Wv+DMM*DMM;   bia=P.bv+DMM;   dst=P.v;   }
    else          { W=P.Wres+DMM*DMM; bia=P.bres+DMM; dst=P.res; }
    const float2 bv2 = *(const float2*)(bia+2*cp);
    float a0=bv2.x, a1=bv2.y;
    const float2* W2 = (const float2*)W;
    #pragma unroll 8
    for (int kk=0; kk<DMM; kk++){
      float2 w2 = W2[kk*64+cp];
      float xv = xloc[kk];
      a0 += xv*w2.x; a1 += xv*w2.y;
    }
    if (m==1){
      float* kT = dst + SS + ((size_t)b*DMM + 2*cp)*NN;
      kT[i] = a0; kT[NN + i] = a1;
    } else {
      *(float2*)(dst + SS + (size_t)row*DMM + 2*cp) = make_float2(a0,a1);
    }
  }
}

// ---------------- D3: attn(l=1) -> out ----------------
__global__ __launch_bounds__(256) void k_attn(Params P){
  const int t = threadIdx.x;
  const int bid = blockIdx.x;
  const int obid = (bid & 7)*128 + (bid >> 3);   // XCD swizzle
  const int b = obid >> 8;
  const int i = obid & 255;
  const int l = P.layer;

  __shared__ float qs[128];
  __shared__ float qwe_s[64];
  __shared__ float qbe_s[8];
  __shared__ float es[8*PS];
  __shared__ float ps[8*PS];
  __shared__ float ssum_s[8];
  __shared__ float g_s[64];
  __shared__ float res_s[128];
  __shared__ float red_a[2], red_b[2], red_c[2];

  if (t < 128) qs[t] = P.q[(b*NN+i)*DMM + t];
  {
    const int j = t;
    const float4* er4 = (const float4*)(P.edges + ((size_t)(b*NN+i)*NN + j)*DEE);
    float4 e0 = er4[0], e1 = er4[1];
    es[0*PS+j]=e0.x; es[1*PS+j]=e0.y; es[2*PS+j]=e0.z; es[3*PS+j]=e0.w;
    es[4*PS+j]=e1.x; es[5*PS+j]=e1.y; es[6*PS+j]=e1.z; es[7*PS+j]=e1.w;
  }
  __syncthreads();
  if (t < 64){
    const int h = t>>3, c = t&7;
    const float* Wer = P.We + l*DEE*DMM + c*DMM + h*DD;
    float a = 0.f;
    #pragma unroll
    for (int d=0; d<DD; d++) a += qs[h*DD+d]*Wer[d];
    qwe_s[t] = a;
    if (c==0){
      const float* ber = P.be + l*DMM + h*DD;
      float a2 = 0.f;
      #pragma unroll
      for (int d=0; d<DD; d++) a2 += qs[h*DD+d]*ber[d];
      qbe_s[h] = a2;
    }
  }
  __syncthreads();

  // ---- phase 1: wave dp -> heads {2dp,2dp+1}; lane jg -> cols 4jg..4jg+3 ----
  {
    const int dp = t>>6, jg = t&63;
    const int J = 4*jg;
    const float4 av = *(const float4*)(P.adjacency + (size_t)(b*NN+i)*NN + J);
    float4 ec4[8];                       // es hoist
    #pragma unroll
    for (int c=0; c<8; c++) ec4[c] = *(const float4*)(&es[c*PS + J]);
    float hsum[2];
    #pragma unroll
    for (int hh=0; hh<2; hh++){
      const int h = 2*dp+hh;
      float qh[16];
      #pragma unroll
      for (int d=0; d<16; d++) qh[d] = qs[h*DD+d];
      float s0=qbe_s[h]; float s1=s0, s2=s0, s3=s0;
      const float* kbase = P.k + ((size_t)b*DMM + h*DD)*NN + J;
      #pragma unroll
      for (int db=0; db<2; db++){
        float4 krg[8];
        #pragma unroll
        for (int d=0; d<8; d++) krg[d] = *(const float4*)(kbase + (size_t)(db*8+d)*NN);
        #pragma unroll
        for (int d=0; d<8; d++){
          float qv = qh[db*8+d];
          s0 += qv*krg[d].x; s1 += qv*krg[d].y; s2 += qv*krg[d].z; s3 += qv*krg[d].w;
        }
      }
      #pragma unroll
      for (int c=0; c<8; c++){
        float wv = qwe_s[h*8+c];
        s0 += wv*ec4[c].x; s1 += wv*ec4[c].y; s2 += wv*ec4[c].z; s3 += wv*ec4[c].w;
      }
      float4 p;
      p.x = __expf(s0*SCALE)*av.x;
      p.y = __expf(s1*SCALE)*av.y;
      p.z = __expf(s2*SCALE)*av.z;
      p.w = __expf(s3*SCALE)*av.w;
      *(float4*)(&ps[h*PS + J]) = p;
      hsum[hh] = (p.x+p.y)+(p.z+p.w);
    }
    float v0 = hsum[0], v1 = hsum[1];
    #pragma unroll
    for (int off=32; off; off>>=1){ v0 += __shfl_xor(v0,off,64); v1 += __shfl_xor(v1,off,64); }
    if (jg==0){ ssum_s[2*dp] = v0; ssum_s[2*dp+1] = v1; }
  }
  __syncthreads();

  // ---- phase 2: pv (t<128), g (t<192), res (else) ----
  float pv = 0.f;
  if (t < 128){
    const int h = t>>4;
    const float* vcol = P.v + (size_t)b*NN*DMM + t;
    const float4* pr = (const float4*)(ps + h*PS);
    #pragma unroll 4
    for (int jq=0; jq<64; jq++){
      float4 pp = pr[jq];
      const float* vv = vcol + jq*4*DMM;
      pv += pp.x*vv[0] + pp.y*vv[DMM] + pp.z*vv[2*DMM] + pp.w*vv[3*DMM];
    }
  } else if (t < 192){
    const int h = (t-128)>>3, c = (t-128)&7;
    const float4* pr = (const float4*)(ps + h*PS);
    const float4* er = (const float4*)(es + c*PS);
    float g = 0.f;
    #pragma unroll 4
    for (int jq=0; jq<64; jq++){
      float4 pp = pr[jq], ee = er[jq];
      g += pp.x*ee.x + pp.y*ee.y + pp.z*ee.z + pp.w*ee.w;
    }
    g_s[h*8+c] = g;
  } else {
    const int u = t - 192;
    const float2 rv = *(const float2*)(P.res + (b*NN+i)*DMM + 2*u);
    res_s[2*u] = rv.x; res_s[2*u+1] = rv.y;
  }
  __syncthreads();

  // ---- phase 3 ----
  float o = 0.f, rr = 0.f;
  if (t < 128){
    const int h = t>>4;
    const float* Wec = P.We + l*DEE*DMM + t;
    float eacc = 0.f;
    #pragma unroll
    for (int c=0;c<8;c++) eacc += Wec[c*DMM] * g_s[h*8+c];
    const float ssum = ssum_s[h];
    const float denom = (ssum==0.f) ? 1.f : ssum;
    const float bev = P.be[l*DMM + t];
    o = (pv + eacc + ssum*bev) / denom;
    rr = res_s[t];
    const float* Wg = P.Wgate + l*3*DMM;
    float contrib = o*Wg[t] + rr*Wg[DMM+t] + (o-rr)*Wg[2*DMM+t];
    #pragma unroll
    for (int off=32; off; off>>=1) contrib += __shfl_xor(contrib, off, 64);
    if ((t&63)==0) red_a[t>>6] = contrib;
  }
  __syncthreads();

  float y = 0.f;
  if (t < 128){
    const float gs = red_a[0] + red_a[1];
    const float gate = 1.f/(1.f + __expf(-gs));
    y = o*gate + rr*(1.f-gate);
    float s1 = y, s2 = y*y;
    #pragma unroll
    for (int off=32; off; off>>=1){ s1 += __shfl_xor(s1, off, 64); s2 += __shfl_xor(s2, off, 64); }
    if ((t&63)==0){ red_b[t>>6] = s1; red_c[t>>6] = s2; }
  }
  __syncthreads();

  if (t < 128){
    const float mu  = (red_b[0]+red_b[1]) * (1.f/128.f);
    const float var = (red_c[0]+red_c[1]) * (1.f/128.f) - mu*mu;
    const float inv = rsqrtf(var + 1e-5f);
    float yn = (y - mu)*inv*P.lng[l*DMM+t] + P.lnb[l*DMM+t];
    yn = fmaxf(yn, 0.f);
    P.out[(b*NN+i)*DMM + t] = yn;
  }
}

extern "C" void kernel_launch(void* const* d_in, const int* in_sizes, int n_in,
                              void* d_out, int out_size, void* d_ws, size_t ws_size,
                              hipStream_t stream) {
  Params P;
  P.nodes     = (const float*)d_in[0];
  P.edges     = (const float*)d_in[1];
  P.adjacency = (const float*)d_in[2];
  P.Wq   = (const float*)d_in[3];  P.bq   = (const float*)d_in[4];
  P.Wk   = (const float*)d_in[5];  P.bk   = (const float*)d_in[6];
  P.Wv   = (const float*)d_in[7];  P.bv   = (const float*)d_in[8];
  P.We   = (const float*)d_in[9];  P.be   = (const float*)d_in[10];
  P.Wres = (const float*)d_in[11]; P.bres = (const float*)d_in[12];
  P.Wgate= (const float*)d_in[13];
  P.lng  = (const float*)d_in[14]; P.lnb  = (const float*)d_in[15];

  float* f = (float*)d_ws;
  float* qbuf = f;            // q0 at +0, q1 at +SS
  float* kbuf = f + 2*SS;     // TRANSPOSED [b][d][j]
  float* vbuf = f + 4*SS;
  float* rbuf = f + 6*SS;
  P.out = (float*)d_out;

  // D1: proj layer 0 (512 blocks x 2 rows)
  P.layer = 0; P.src = P.nodes;
  P.q = qbuf; P.k = kbuf; P.v = vbuf; P.res = rbuf;
  hipLaunchKernelGGL(k_proj, dim3(BB*NN/2), dim3(256), 0, stream, P);

  // D2: attn(l0) 1 row/block + proj(l1)
  hipLaunchKernelGGL(k_mid, dim3(BB*NN), dim3(256), 0, stream, P);

  // D3: attn(l1) -> out
  P.layer = 1;
  P.q = qbuf + SS; P.k = kbuf + SS; P.v = vbuf + SS; P.res = rbuf + SS;
  hipLaunchKernelGGL(k_attn, dim3(BB*NN), dim3(256), 0, stream, P);
}

// Round 13
// 142.752 us; speedup vs baseline: 1.0114x; 1.0114x over previous
//
#include <hip/hip_runtime.h>

#define BB 4
#define NN 256
#define DMM 128
#define DEE 8
#define HH 8
#define DD 16
#define LAYERS 2
#define SCALE 0.25f
#define PS 260               // padded LDS stride (floats); 260%4==0 so float4-aligned rows
#define SS (BB*NN*DMM)       // 131072 floats per per-layer buffer

// FINAL (V11, measured best 143.56us; baseline 158.0us):
// - K stored TRANSPOSED: kT[b][d][j] at ((b*DMM + d)*NN + j). R7's one big win
//   (-24us): QK^T reads become lane-consecutive (4 lines/wave-instr vs 64).
// - 3-dispatch structure (minimum: proj0 | attn0+proj1 | attn1; in-kernel grid
//   sync measured 145-150us/sync on this chip - R3/R4).
// - XCD-aware blockIdx swizzle (T1): blocks sharing a batch's K/V panels land
//   on one XCD's L2 (+es hoist, paired K^T stores) - R11, -2-3us.
// - Isolated nulls (do not re-add): deeper ILP/prefetch in PV (R9/R10),
//   wave-occupancy increases (R6), instruction-count cuts beyond K^T (R8).

struct Params {
  const float *nodes, *edges, *adjacency;
  const float *Wq, *bq, *Wk, *bk, *Wv, *bv, *We, *be, *Wres, *bres, *Wgate, *lng, *lnb;
  const float *src;
  float *q, *k, *v, *res;
  float *out;
  int layer;
};

// ---------------- D1: q,k,v,res = src @ W + b (layer 0); 512 blocks x 2 rows ----------------
__global__ __launch_bounds__(256) void k_proj(Params P){
  const int t = threadIdx.x;
  const int m = t >> 6;
  const int cp = t & 63;
  const int bid = blockIdx.x;
  const int obid = (bid & 7)*64 + (bid >> 3);    // XCD swizzle
  const int row0 = obid * 2;
  const int l = P.layer;
  const float *W, *bia; float* dst;
  if (m==0){ W = P.Wq + l*DMM*DMM; bia = P.bq + l*DMM; dst = P.q; }
  else if (m==1){ W = P.Wk + l*DMM*DMM; bia = P.bk + l*DMM; dst = P.k; }
  else if (m==2){ W = P.Wv + l*DMM*DMM; bia = P.bv + l*DMM; dst = P.v; }
  else { W = P.Wres + l*DMM*DMM; bia = P.bres + l*DMM; dst = P.res; }
  const float2 bv2 = *(const float2*)(bia + 2*cp);
  float a00=bv2.x, a01=bv2.y, a10=bv2.x, a11=bv2.y;
  const float2* W2 = (const float2*)W;
  const float* xr = P.src + (size_t)row0*DMM;
  #pragma unroll 8
  for (int kk=0; kk<DMM; kk++){
    float2 w = W2[kk*64+cp];
    float x0 = xr[kk], x1 = xr[DMM+kk];
    a00 += x0*w.x; a01 += x0*w.y;
    a10 += x1*w.x; a11 += x1*w.y;
  }
  if (m==1){
    const int b = row0 >> 8, i0 = row0 & 255;   // i0 even -> float2-aligned
    float* kT = dst + ((size_t)b*DMM + 2*cp)*NN;
    *(float2*)(kT + i0)      = make_float2(a00, a10);
    *(float2*)(kT + NN + i0) = make_float2(a01, a11);
  } else {
    *(float2*)(dst + (size_t)row0*DMM     + 2*cp) = make_float2(a00,a01);
    *(float2*)(dst + (size_t)(row0+1)*DMM + 2*cp) = make_float2(a10,a11);
  }
}

// ---------------- D2: attn(l=0) for 2 CONCURRENT rows + proj(l=1) ----------------
// NOTE: reference's mean-shift cancels exactly in _adj_softmax - no shift applied.
__global__ __launch_bounds__(512) void k_mid(Params P){
  const int t = threadIdx.x;
  const int r = t >> 8;            // concurrent row index
  const int u = t & 255;           // index within sub-block
  const int bid = blockIdx.x;
  const int obid = (bid & 7)*64 + (bid >> 3);    // XCD swizzle
  const int row0 = obid*2;
  const int row  = row0 + r;
  const int b = row0 >> 8;         // adjacent rows -> same batch

  __shared__ float xloc[2][128];
  __shared__ float qs[2][128];
  __shared__ float res_s[2][128];
  __shared__ float qwe_s[2][64];
  __shared__ float qbe_s[2][8];
  __shared__ float es[2][8*PS];
  __shared__ float ps[2][8*PS];
  __shared__ float ssum_s[2][8];
  __shared__ float g_s[2][64];
  __shared__ float red_a[2][2], red_b[2][2], red_c[2][2];

  // ---- load q0/res0 rows, edge row -> es ----
  if (u < 128) qs[r][u]        = P.q  [(size_t)row*DMM + u];
  else         res_s[r][u-128] = P.res[(size_t)row*DMM + (u-128)];
  {
    const int j = u;
    const float4* er4 = (const float4*)(P.edges + ((size_t)row*NN + j)*DEE);
    float4 e0 = er4[0], e1 = er4[1];
    es[r][0*PS+j]=e0.x; es[r][1*PS+j]=e0.y; es[r][2*PS+j]=e0.z; es[r][3*PS+j]=e0.w;
    es[r][4*PS+j]=e1.x; es[r][5*PS+j]=e1.y; es[r][6*PS+j]=e1.z; es[r][7*PS+j]=e1.w;
  }
  __syncthreads();

  // ---- q-side edge projections (layer 0 weights), per sub-block ----
  if (u < 64){
    const int h = u>>3, c = u&7;
    const float* Wer = P.We + c*DMM + h*DD;
    float a = 0.f;
    #pragma unroll
    for (int d=0; d<DD; d++) a += qs[r][h*DD+d]*Wer[d];
    qwe_s[r][u] = a;
    if (c==0){
      const float* ber = P.be + h*DD;
      float a2=0.f;
      #pragma unroll
      for (int d=0; d<DD; d++) a2 += qs[r][h*DD+d]*ber[d];
      qbe_s[r][h] = a2;
    }
  }
  __syncthreads();

  // ---- phase 1: wave dp -> heads {2dp,2dp+1}; lane jg -> cols 4jg..4jg+3 ----
  {
    const int dp = u>>6, jg = u&63;
    const int J = 4*jg;
    const float4 av = *(const float4*)(P.adjacency + (size_t)row*NN + J);
    float4 ec4[8];                       // es hoist: read once, reuse for both heads
    #pragma unroll
    for (int c=0; c<8; c++) ec4[c] = *(const float4*)(&es[r][c*PS + J]);
    float hsum[2];
    #pragma unroll
    for (int hh=0; hh<2; hh++){
      const int h = 2*dp+hh;
      float qh[16];
      #pragma unroll
      for (int d=0; d<16; d++) qh[d] = qs[r][h*DD+d];
      float s0=qbe_s[r][h]; float s1=s0, s2=s0, s3=s0;
      const float* kbase = P.k + ((size_t)b*DMM + h*DD)*NN + J;
      #pragma unroll
      for (int db=0; db<2; db++){
        float4 krg[8];
        #pragma unroll
        for (int d=0; d<8; d++) krg[d] = *(const float4*)(kbase + (size_t)(db*8+d)*NN);
        #pragma unroll
        for (int d=0; d<8; d++){
          float qv = qh[db*8+d];
          s0 += qv*krg[d].x; s1 += qv*krg[d].y; s2 += qv*krg[d].z; s3 += qv*krg[d].w;
        }
      }
      #pragma unroll
      for (int c=0; c<8; c++){
        float wv = qwe_s[r][h*8+c];
        s0 += wv*ec4[c].x; s1 += wv*ec4[c].y; s2 += wv*ec4[c].z; s3 += wv*ec4[c].w;
      }
      float4 p;
      p.x = __expf(s0*SCALE)*av.x;
      p.y = __expf(s1*SCALE)*av.y;
      p.z = __expf(s2*SCALE)*av.z;
      p.w = __expf(s3*SCALE)*av.w;
      *(float4*)(&ps[r][h*PS + J]) = p;
      hsum[hh] = (p.x+p.y)+(p.z+p.w);
    }
    float v0 = hsum[0], v1 = hsum[1];
    #pragma unroll
    for (int off=32; off; off>>=1){ v0 += __shfl_xor(v0,off,64); v1 += __shfl_xor(v1,off,64); }
    if (jg==0){ ssum_s[r][2*dp] = v0; ssum_s[r][2*dp+1] = v1; }
  }
  __syncthreads();

  // ---- phase 2: pv (u<128), g (128<=u<192) ----
  float pv = 0.f;
  if (u < 128){
    const int h = u>>4;
    const float* vcol = P.v + (size_t)b*NN*DMM + u;     // h*DD+d == u
    const float4* pr = (const float4*)(&ps[r][h*PS]);
    #pragma unroll 4
    for (int jq=0; jq<64; jq++){
      float4 pp = pr[jq];
      const float* vv = vcol + jq*4*DMM;
      pv += pp.x*vv[0] + pp.y*vv[DMM] + pp.z*vv[2*DMM] + pp.w*vv[3*DMM];
    }
  } else if (u < 192){
    const int h=(u-128)>>3, c=(u-128)&7;
    const float4* pr = (const float4*)(&ps[r][h*PS]);
    const float4* er = (const float4*)(&es[r][c*PS]);
    float g=0.f;
    #pragma unroll 4
    for (int jq=0; jq<64; jq++){
      float4 pp=pr[jq], ee=er[jq];
      g += pp.x*ee.x + pp.y*ee.y + pp.z*ee.z + pp.w*ee.w;
    }
    g_s[r][h*8+c]=g;
  }
  __syncthreads();

  // ---- phase 3: assemble out, gate reduction (layer 0 weights) ----
  float o=0.f, rr=0.f;
  if (u<128){
    const int h = u>>4;
    const float* Wec = P.We + u;
    float eacc=0.f;
    #pragma unroll
    for (int c=0;c<8;c++) eacc += Wec[c*DMM]*g_s[r][h*8+c];
    const float ssum = ssum_s[r][h];
    const float denom = (ssum==0.f)?1.f:ssum;
    const float bev = P.be[u];
    o = (pv + eacc + ssum*bev)/denom;
    rr = res_s[r][u];
    const float* Wg = P.Wgate;
    float contrib = o*Wg[u] + rr*Wg[DMM+u] + (o-rr)*Wg[2*DMM+u];
    #pragma unroll
    for (int off=32; off; off>>=1) contrib += __shfl_xor(contrib, off, 64);
    if ((u&63)==0) red_a[r][u>>6]=contrib;
  }
  __syncthreads();

  float y=0.f;
  if (u<128){
    const float gs = red_a[r][0]+red_a[r][1];
    const float gate = 1.f/(1.f+__expf(-gs));
    y = o*gate + rr*(1.f-gate);
    float s1=y, s2=y*y;
    #pragma unroll
    for (int off=32; off; off>>=1){ s1+=__shfl_xor(s1,off,64); s2+=__shfl_xor(s2,off,64); }
    if ((u&63)==0){ red_b[r][u>>6]=s1; red_c[r][u>>6]=s2; }
  }
  __syncthreads();

  if (u<128){
    const float mu  = (red_b[r][0]+red_b[r][1])*(1.f/128.f);
    const float var = (red_c[r][0]+red_c[r][1])*(1.f/128.f) - mu*mu;
    const float inv = rsqrtf(var+1e-5f);
    float yn = (y-mu)*inv*P.lng[u] + P.lnb[u];
    xloc[r][u] = fmaxf(yn, 0.f);
  }
  __syncthreads();

  // ---- proj(l=1) for both rows: wave w -> matrix w&3, row w>>2 ----
  {
    const int w = t>>6, m = w&3, ri = w>>2, cp = t&63;
    const float *W, *bia; float* dst;
    if (m==0){ W=P.Wq+DMM*DMM;   bia=P.bq+DMM;   dst=P.q;   }
    else if (m==1){ W=P.Wk+DMM*DMM;   bia=P.bk+DMM;   dst=P.k;   }
    else if (m==2){ W=P.Wv+DMM*DMM;   bia=P.bv+DMM;   dst=P.v;   }
    else          { W=P.Wres+DMM*DMM; bia=P.bres+DMM; dst=P.res; }
    const float2 bv2 = *(const float2*)(bia+2*cp);
    float a0=bv2.x, a1=bv2.y;
    const float2* W2 = (const float2*)W;
    const float* xr = xloc[ri];
    #pragma unroll 8
    for (int kk=0; kk<DMM; kk++){
      float2 w2 = W2[kk*64+cp];
      float xv = xr[kk];
      a0 += xv*w2.x; a1 += xv*w2.y;
    }
    const int prow = row0 + ri;
    if (m==1){
      const int pb = prow >> 8, pi = prow & 255;
      float* kT = dst + SS + ((size_t)pb*DMM + 2*cp)*NN;
      kT[pi] = a0; kT[NN + pi] = a1;
    } else {
      *(float2*)(dst + SS + (size_t)prow*DMM + 2*cp) = make_float2(a0,a1);
    }
  }
}

// ---------------- D3: attn(l=1) -> out ----------------
__global__ __launch_bounds__(256) void k_attn(Params P){
  const int t = threadIdx.x;
  const int bid = blockIdx.x;
  const int obid = (bid & 7)*128 + (bid >> 3);   // XCD swizzle
  const int b = obid >> 8;
  const int i = obid & 255;
  const int l = P.layer;

  __shared__ float qs[128];
  __shared__ float qwe_s[64];
  __shared__ float qbe_s[8];
  __shared__ float es[8*PS];
  __shared__ float ps[8*PS];
  __shared__ float ssum_s[8];
  __shared__ float g_s[64];
  __shared__ float res_s[128];
  __shared__ float red_a[2], red_b[2], red_c[2];

  if (t < 128) qs[t] = P.q[(b*NN+i)*DMM + t];
  {
    const int j = t;
    const float4* er4 = (const float4*)(P.edges + ((size_t)(b*NN+i)*NN + j)*DEE);
    float4 e0 = er4[0], e1 = er4[1];
    es[0*PS+j]=e0.x; es[1*PS+j]=e0.y; es[2*PS+j]=e0.z; es[3*PS+j]=e0.w;
    es[4*PS+j]=e1.x; es[5*PS+j]=e1.y; es[6*PS+j]=e1.z; es[7*PS+j]=e1.w;
  }
  __syncthreads();
  if (t < 64){
    const int h = t>>3, c = t&7;
    const float* Wer = P.We + l*DEE*DMM + c*DMM + h*DD;
    float a = 0.f;
    #pragma unroll
    for (int d=0; d<DD; d++) a += qs[h*DD+d]*Wer[d];
    qwe_s[t] = a;
    if (c==0){
      const float* ber = P.be + l*DMM + h*DD;
      float a2 = 0.f;
      #pragma unroll
      for (int d=0; d<DD; d++) a2 += qs[h*DD+d]*ber[d];
      qbe_s[h] = a2;
    }
  }
  __syncthreads();

  // ---- phase 1: wave dp -> heads {2dp,2dp+1}; lane jg -> cols 4jg..4jg+3 ----
  {
    const int dp = t>>6, jg = t&63;
    const int J = 4*jg;
    const float4 av = *(const float4*)(P.adjacency + (size_t)(b*NN+i)*NN + J);
    float4 ec4[8];                       // es hoist
    #pragma unroll
    for (int c=0; c<8; c++) ec4[c] = *(const float4*)(&es[c*PS + J]);
    float hsum[2];
    #pragma unroll
    for (int hh=0; hh<2; hh++){
      const int h = 2*dp+hh;
      float qh[16];
      #pragma unroll
      for (int d=0; d<16; d++) qh[d] = qs[h*DD+d];
      float s0=qbe_s[h]; float s1=s0, s2=s0, s3=s0;
      const float* kbase = P.k + ((size_t)b*DMM + h*DD)*NN + J;
      #pragma unroll
      for (int db=0; db<2; db++){
        float4 krg[8];
        #pragma unroll
        for (int d=0; d<8; d++) krg[d] = *(const float4*)(kbase + (size_t)(db*8+d)*NN);
        #pragma unroll
        for (int d=0; d<8; d++){
          float qv = qh[db*8+d];
          s0 += qv*krg[d].x; s1 += qv*krg[d].y; s2 += qv*krg[d].z; s3 += qv*krg[d].w;
        }
      }
      #pragma unroll
      for (int c=0; c<8; c++){
        float wv = qwe_s[h*8+c];
        s0 += wv*ec4[c].x; s1 += wv*ec4[c].y; s2 += wv*ec4[c].z; s3 += wv*ec4[c].w;
      }
      float4 p;
      p.x = __expf(s0*SCALE)*av.x;
      p.y = __expf(s1*SCALE)*av.y;
      p.z = __expf(s2*SCALE)*av.z;
      p.w = __expf(s3*SCALE)*av.w;
      *(float4*)(&ps[h*PS + J]) = p;
      hsum[hh] = (p.x+p.y)+(p.z+p.w);
    }
    float v0 = hsum[0], v1 = hsum[1];
    #pragma unroll
    for (int off=32; off; off>>=1){ v0 += __shfl_xor(v0,off,64); v1 += __shfl_xor(v1,off,64); }
    if (jg==0){ ssum_s[2*dp] = v0; ssum_s[2*dp+1] = v1; }
  }
  __syncthreads();

  // ---- phase 2: pv (t<128), g (t<192), res (else) ----
  float pv = 0.f;
  if (t < 128){
    const int h = t>>4;
    const float* vcol = P.v + (size_t)b*NN*DMM + t;
    const float4* pr = (const float4*)(ps + h*PS);
    #pragma unroll 4
    for (int jq=0; jq<64; jq++){
      float4 pp = pr[jq];
      const float* vv = vcol + jq*4*DMM;
      pv += pp.x*vv[0] + pp.y*vv[DMM] + pp.z*vv[2*DMM] + pp.w*vv[3*DMM];
    }
  } else if (t < 192){
    const int h = (t-128)>>3, c = (t-128)&7;
    const float4* pr = (const float4*)(ps + h*PS);
    const float4* er = (const float4*)(es + c*PS);
    float g = 0.f;
    #pragma unroll 4
    for (int jq=0; jq<64; jq++){
      float4 pp = pr[jq], ee = er[jq];
      g += pp.x*ee.x + pp.y*ee.y + pp.z*ee.z + pp.w*ee.w;
    }
    g_s[h*8+c] = g;
  } else {
    const int u = t - 192;
    const float2 rv = *(const float2*)(P.res + (b*NN+i)*DMM + 2*u);
    res_s[2*u] = rv.x; res_s[2*u+1] = rv.y;
  }
  __syncthreads();

  // ---- phase 3 ----
  float o = 0.f, rr = 0.f;
  if (t < 128){
    const int h = t>>4;
    const float* Wec = P.We + l*DEE*DMM + t;
    float eacc = 0.f;
    #pragma unroll
    for (int c=0;c<8;c++) eacc += Wec[c*DMM] * g_s[h*8+c];
    const float ssum = ssum_s[h];
    const float denom = (ssum==0.f) ? 1.f : ssum;
    const float bev = P.be[l*DMM + t];
    o = (pv + eacc + ssum*bev) / denom;
    rr = res_s[t];
    const float* Wg = P.Wgate + l*3*DMM;
    float contrib = o*Wg[t] + rr*Wg[DMM+t] + (o-rr)*Wg[2*DMM+t];
    #pragma unroll
    for (int off=32; off; off>>=1) contrib += __shfl_xor(contrib, off, 64);
    if ((t&63)==0) red_a[t>>6] = contrib;
  }
  __syncthreads();

  float y = 0.f;
  if (t < 128){
    const float gs = red_a[0] + red_a[1];
    const float gate = 1.f/(1.f + __expf(-gs));
    y = o*gate + rr*(1.f-gate);
    float s1 = y, s2 = y*y;
    #pragma unroll
    for (int off=32; off; off>>=1){ s1 += __shfl_xor(s1, off, 64); s2 += __shfl_xor(s2, off, 64); }
    if ((t&63)==0){ red_b[t>>6] = s1; red_c[t>>6] = s2; }
  }
  __syncthreads();

  if (t < 128){
    const float mu  = (red_b[0]+red_b[1]) * (1.f/128.f);
    const float var = (red_c[0]+red_c[1]) * (1.f/128.f) - mu*mu;
    const float inv = rsqrtf(var + 1e-5f);
    float yn = (y - mu)*inv*P.lng[l*DMM+t] + P.lnb[l*DMM+t];
    yn = fmaxf(yn, 0.f);
    P.out[(b*NN+i)*DMM + t] = yn;
  }
}

extern "C" void kernel_launch(void* const* d_in, const int* in_sizes, int n_in,
                              void* d_out, int out_size, void* d_ws, size_t ws_size,
                              hipStream_t stream) {
  Params P;
  P.nodes     = (const float*)d_in[0];
  P.edges     = (const float*)d_in[1];
  P.adjacency = (const float*)d_in[2];
  P.Wq   = (const float*)d_in[3];  P.bq   = (const float*)d_in[4];
  P.Wk   = (const float*)d_in[5];  P.bk   = (const float*)d_in[6];
  P.Wv   = (const float*)d_in[7];  P.bv   = (const float*)d_in[8];
  P.We   = (const float*)d_in[9];  P.be   = (const float*)d_in[10];
  P.Wres = (const float*)d_in[11]; P.bres = (const float*)d_in[12];
  P.Wgate= (const float*)d_in[13];
  P.lng  = (const float*)d_in[14]; P.lnb  = (const float*)d_in[15];

  float* f = (float*)d_ws;
  float* qbuf = f;            // q0 at +0, q1 at +SS
  float* kbuf = f + 2*SS;     // TRANSPOSED [b][d][j]
  float* vbuf = f + 4*SS;
  float* rbuf = f + 6*SS;
  P.out = (float*)d_out;

  // D1: proj layer 0 (512 blocks x 2 rows)
  P.layer = 0; P.src = P.nodes;
  P.q = qbuf; P.k = kbuf; P.v = vbuf; P.res = rbuf;
  hipLaunchKernelGGL(k_proj, dim3(BB*NN/2), dim3(256), 0, stream, P);

  // D2: attn(l0, 2 concurrent rows) + proj(l1)
  hipLaunchKernelGGL(k_mid, dim3(BB*NN/2), dim3(512), 0, stream, P);

  // D3: attn(l1) -> out
  P.layer = 1;
  P.q = qbuf + SS; P.k = kbuf + SS; P.v = vbuf + SS; P.res = rbuf + SS;
  hipLaunchKernelGGL(k_attn, dim3(BB*NN), dim3(256), 0, stream, P);
}